// Round 2
// baseline (22.417 us; speedup 1.0000x reference)
//
#include <hip/hip_runtime.h>
#include <math.h>

// Problem constants (from reference setup_inputs):
//   X: (B=32, A=3, S=52, S=52, D=85) f32 ; yboxes: (32,20,4) f32 ;
//   ylabels: (32,20) i32 ; anchors: (3,2) f32 ; nclasses=80
// Reference quirk: wgrid = X.shape[-4] = A = 3 (NOT 52); hgrid = 52.
#define BB    32
#define AA    3
#define SS    52
#define DD    85
#define NN    20
#define NCLS  80
#define KK    (BB * NN)          // 640 boxes
#define WGRID 3
#define HGRID 52
#define HW    (HGRID * WGRID)    // 156 cells
#define BIGV  (1 << 30)
#define NTHREADS 1024            // 16 waves, single block (one CU)

// Single fused kernel: first-claim scatter-min in LDS, then per-(box,anchor)
// loss tasks, then deterministic block reduction and a plain store to out.
__global__ void __launch_bounds__(NTHREADS)
yolo_fused_kernel(const float* __restrict__ X,
                  const float* __restrict__ yboxes,
                  const int* __restrict__ ylabels,
                  const float* __restrict__ anchors,
                  float* __restrict__ out) {
    __shared__ int   first[HW];
    __shared__ float sdata[NTHREADS / 64];

    const int tid = threadIdx.x;

    // Phase 1: first-claim index per cell (global across the whole batch,
    // matching the reference's single hgrid*wgrid scatter-min).
    if (tid < HW) first[tid] = BIGV;
    __syncthreads();
    if (tid < KK) {
        float bx = yboxes[4 * tid + 0];
        float by = yboxes[4 * tid + 1];
        int x = (int)floorf(bx * (float)WGRID);   // in [0,2]
        int y = (int)floorf(by * (float)HGRID);   // in [0,51]
        atomicMin(&first[y * WGRID + x], tid);
    }
    __syncthreads();

    // Phase 2: one task per (box k, anchor a); stride over 1920 tasks.
    float acc = 0.0f;
    for (int t = tid; t < KK * AA; t += NTHREADS) {
        int k = t / AA;
        int a = t - k * AA;
        float bx = yboxes[4 * k + 0];
        float by = yboxes[4 * k + 1];
        int x = (int)floorf(bx * (float)WGRID);
        int y = (int)floorf(by * (float)HGRID);
        if (first[y * WGRID + x] != k) continue;  // not first box in cell

        float bw = yboxes[4 * k + 2];
        float bh = yboxes[4 * k + 3];
        int img = k / NN;
        const float* __restrict__ P =
            X + ((((size_t)img * AA + a) * SS + y) * SS + x) * DD;

        // Gather the 85-float row into registers (constant indices only).
        float p[DD];
#pragma unroll
        for (int d = 0; d < DD; ++d) p[d] = P[d];

        // obj = softplus(-p0), numerically stable (matches jax.nn.softplus)
        float z = -p[0];
        float obj = fmaxf(z, 0.0f) + log1pf(expf(-fabsf(z)));

        // box MSE vs target [xrel, yrel, w/anchor_w, h/anchor_h]
        float xrel = bx * (float)WGRID - (float)x;
        float yrel = by * (float)HGRID - (float)y;
        float wc = bw / anchors[2 * a + 0];
        float hc = bh / anchors[2 * a + 1];
        float d1 = p[1] - xrel, d2 = p[2] - yrel;
        float d3 = p[3] - wc,   d4 = p[4] - hc;
        float boxl = 0.25f * (d1 * d1 + d2 * d2 + d3 * d3 + d4 * d4);

        // class NLL from log_softmax over p[5..84]
        float m = -INFINITY;
#pragma unroll
        for (int c = 0; c < NCLS; ++c) m = fmaxf(m, p[5 + c]);
        float ssum = 0.0f;
#pragma unroll
        for (int c = 0; c < NCLS; ++c) ssum += expf(p[5 + c] - m);
        int lab = ylabels[k];
        // dynamic index: load straight from global (L1-hot) to avoid
        // forcing the p[] register array into scratch (rule #20)
        float plab = P[5 + lab];
        float clsl = -(plab - m - logf(ssum));

        acc += 1.0f * obj + 10.0f * boxl + 1.0f * clsl;
    }

    // Phase 3: deterministic block reduction; no atomics, plain final store.
    const int lane = tid & 63;
    const int wave = tid >> 6;
#pragma unroll
    for (int off = 32; off > 0; off >>= 1) acc += __shfl_down(acc, off, 64);
    if (lane == 0) sdata[wave] = acc;
    __syncthreads();
    if (wave == 0) {
        float w = (lane < NTHREADS / 64) ? sdata[lane] : 0.0f;
#pragma unroll
        for (int off = 32; off > 0; off >>= 1) w += __shfl_down(w, off, 64);
        if (lane == 0) out[0] = w;
    }
}

extern "C" void kernel_launch(void* const* d_in, const int* in_sizes, int n_in,
                              void* d_out, int out_size, void* d_ws, size_t ws_size,
                              hipStream_t stream) {
    const float* X       = (const float*)d_in[0];
    const float* yboxes  = (const float*)d_in[1];
    const int*   ylabels = (const int*)d_in[2];
    const float* anchors = (const float*)d_in[3];
    // d_in[4] = nclasses scalar (80), hard-coded above.

    float* out = (float*)d_out;

    yolo_fused_kernel<<<1, NTHREADS, 0, stream>>>(X, yboxes, ylabels, anchors,
                                                  out);
}

// Round 3
// 17.975 us; speedup vs baseline: 1.2471x; 1.2471x over previous
//
#include <hip/hip_runtime.h>
#include <math.h>

// Problem constants (from reference setup_inputs):
//   X: (B=32, A=3, S=52, S=52, D=85) f32 ; yboxes: (32,20,4) f32 ;
//   ylabels: (32,20) i32 ; anchors: (3,2) f32 ; nclasses=80
// Reference quirk: wgrid = X.shape[-4] = A = 3 (NOT 52); hgrid = 52.
#define BB    32
#define AA    3
#define SS    52
#define DD    85
#define NN    20
#define NCLS  80
#define KK    (BB * NN)          // 640 boxes
#define WGRID 3
#define HGRID 52
#define HW    (HGRID * WGRID)    // 156 cells
#define BIGV  (1 << 30)
#define NEGINF (-__builtin_inff())

// d_ws layout (ints): [0] = count, [1 .. 1+HW) = compacted contributor list
// Max contributors = HW = 156  ->  max tasks = 468 = 117 blocks * 4 waves.

// Kernel 1 (1 block): scatter-min first-claim per cell, compact contributor
// list into d_ws, zero the output.
__global__ void __launch_bounds__(256)
yolo_prep_kernel(const float* __restrict__ yboxes,
                 int* __restrict__ ws,
                 float* __restrict__ out) {
    __shared__ int first[HW];
    __shared__ int cnt;
    const int tid = threadIdx.x;
    if (tid < HW) first[tid] = BIGV;
    if (tid == 0) cnt = 0;
    __syncthreads();

    const float4* __restrict__ b4 = (const float4*)yboxes;
    for (int k = tid; k < KK; k += 256) {
        float4 b = b4[k];
        int x = (int)floorf(b.x * (float)WGRID);   // [0,2]
        int y = (int)floorf(b.y * (float)HGRID);   // [0,51]
        atomicMin(&first[y * WGRID + x], k);
    }
    __syncthreads();

    if (tid < HW) {
        int f = first[tid];
        if (f < BIGV) {
            int slot = atomicAdd(&cnt, 1);
            ws[1 + slot] = f;                      // contributing box index
        }
    }
    __syncthreads();
    if (tid == 0) {
        ws[0] = cnt;
        out[0] = 0.0f;
    }
}

// Kernel 2: one wave per (contributor, anchor) task. Coalesced 85-float row
// load (2 loads/lane), butterfly softmax over 64 lanes, lane-0 atomicAdd.
__global__ void __launch_bounds__(256)
yolo_loss_kernel(const float* __restrict__ X,
                 const float* __restrict__ yboxes,
                 const int* __restrict__ ylabels,
                 const float* __restrict__ anchors,
                 const int* __restrict__ ws,
                 float* __restrict__ out) {
    const int wave = (blockIdx.x * 256 + threadIdx.x) >> 6;  // 0..467
    const int lane = threadIdx.x & 63;

    const int cnt = ws[0];                 // <= 156
    const int kidx = wave / 3;
    if (kidx >= cnt) return;               // whole wave exits together
    const int a = wave - 3 * kidx;

    const int k = ws[1 + kidx];
    const float4 bb = ((const float4*)yboxes)[k];
    const int lab = ylabels[k];
    const float2 anc = ((const float2*)anchors)[a];

    const int x = (int)floorf(bb.x * (float)WGRID);
    const int y = (int)floorf(bb.y * (float)HGRID);
    const int img = k / NN;

    const float* __restrict__ P =
        X + ((((size_t)img * AA + a) * SS + y) * SS + x) * DD;

    // coalesced row gather: lane l holds p[l]; lanes 0..20 also hold p[64+l]
    float e0 = P[lane];
    float e1 = NEGINF;
    if (lane < 21) e1 = P[64 + lane];

    // max over class logits p[5..84]
    float v = fmaxf((lane >= 5) ? e0 : NEGINF, (lane < 21) ? e1 : NEGINF);
#pragma unroll
    for (int m = 1; m < 64; m <<= 1) v = fmaxf(v, __shfl_xor(v, m, 64));
    const float mx = v;   // broadcast to all lanes

    // sum of exp(class - mx)
    float s = ((lane >= 5) ? expf(e0 - mx) : 0.0f) +
              ((lane < 21) ? expf(e1 - mx) : 0.0f);
#pragma unroll
    for (int m = 1; m < 64; m <<= 1) s += __shfl_xor(s, m, 64);

    // selected class logit (uniform dynamic index -> broadcast shuffle)
    const int idx = 5 + lab;                     // 5..84
    const float plab = (idx < 64) ? __shfl(e0, idx, 64)
                                  : __shfl(e1, idx - 64, 64);

    // head elements p0..p4
    const float p0 = __shfl(e0, 0, 64);
    const float p1 = __shfl(e0, 1, 64);
    const float p2 = __shfl(e0, 2, 64);
    const float p3 = __shfl(e0, 3, 64);
    const float p4 = __shfl(e0, 4, 64);

    // obj = softplus(-p0), numerically stable
    const float z = -p0;
    const float obj = fmaxf(z, 0.0f) + log1pf(expf(-fabsf(z)));

    // box MSE vs target
    const float xrel = bb.x * (float)WGRID - (float)x;
    const float yrel = bb.y * (float)HGRID - (float)y;
    const float wc = bb.z / anc.x;
    const float hc = bb.w / anc.y;
    const float d1 = p1 - xrel, d2 = p2 - yrel, d3 = p3 - wc, d4 = p4 - hc;
    const float boxl = 0.25f * (d1 * d1 + d2 * d2 + d3 * d3 + d4 * d4);

    // class NLL
    const float clsl = -(plab - mx - logf(s));

    const float per = obj + 10.0f * boxl + clsl;
    if (lane == 0) atomicAdd(out, per);
}

extern "C" void kernel_launch(void* const* d_in, const int* in_sizes, int n_in,
                              void* d_out, int out_size, void* d_ws, size_t ws_size,
                              hipStream_t stream) {
    const float* X       = (const float*)d_in[0];
    const float* yboxes  = (const float*)d_in[1];
    const int*   ylabels = (const int*)d_in[2];
    const float* anchors = (const float*)d_in[3];
    // d_in[4] = nclasses scalar (80), hard-coded above.

    float* out = (float*)d_out;
    int*   ws  = (int*)d_ws;

    yolo_prep_kernel<<<1, 256, 0, stream>>>(yboxes, ws, out);

    // max tasks = HW*AA = 468 waves = 117 blocks of 4 waves
    yolo_loss_kernel<<<(HW * AA) / 4, 256, 0, stream>>>(X, yboxes, ylabels,
                                                        anchors, ws, out);
}